// Round 5
// baseline (444.891 us; speedup 1.0000x reference)
//
#include <hip/hip_runtime.h>
#include <hip/hip_bf16.h>

typedef unsigned short u16;
typedef unsigned int u32;
typedef __bf16 bf16x8 __attribute__((ext_vector_type(8)));
typedef float f32x4 __attribute__((ext_vector_type(4)));

#define SEQ 2048
#define NH 16
#define PD 64
#define DM 1024

__device__ __forceinline__ float bf2f(u16 s) {
  u32 t = ((u32)s) << 16;
  float f;
  __builtin_memcpy(&f, &t, 4);
  return f;
}
__device__ __forceinline__ u16 f2bf(float f) {
  u32 x;
  __builtin_memcpy(&x, &f, 4);
  x = (x + 0x7fffu + ((x >> 16) & 1u)) >> 16;
  return (u16)x;
}
__device__ __forceinline__ float u2f(u32 b) {
  float f;
  __builtin_memcpy(&f, &b, 4);
  return f;
}
__device__ __forceinline__ u32 pack2(float a, float b) {
  __hip_bfloat162 h = __float22bfloat162_rn(float2{a, b});
  u32 r;
  __builtin_memcpy(&r, &h, 4);
  return r;
}
template <int C>
__device__ __forceinline__ float dppf(float x) {
  int xi;
  __builtin_memcpy(&xi, &x, 4);
  int yi = __builtin_amdgcn_mov_dpp(xi, C, 0xF, 0xF, false);
  float y;
  __builtin_memcpy(&y, &yi, 4);
  return y;
}
__device__ __forceinline__ float rmax16(float x) {
  x = fmaxf(x, dppf<0x121>(x));
  x = fmaxf(x, dppf<0x122>(x));
  x = fmaxf(x, dppf<0x124>(x));
  x = fmaxf(x, dppf<0x128>(x));
  return x;
}
__device__ __forceinline__ float rsum16(float x) {
  x += dppf<0x121>(x);
  x += dppf<0x122>(x);
  x += dppf<0x124>(x);
  x += dppf<0x128>(x);
  return x;
}
// async global -> LDS, 16B per lane. lds dest = wave-uniform base + lane*16B.
__device__ __forceinline__ void gld16(const u16* g, u16* l) {
  __builtin_amdgcn_global_load_lds(
      (const __attribute__((address_space(1))) unsigned int*)(g),
      (__attribute__((address_space(3))) unsigned int*)(l), 16, 0, 0);
}

// ---------------- dtype detection (fp32 vs bf16 input buffers) ----------------
__global__ __launch_bounds__(256) void detect_kernel(const u16* __restrict__ probe,
                                                     int* __restrict__ flag) {
  __shared__ int sz[256], sh[256];
  int tid = threadIdx.x;
  int zeros = 0, huge = 0;
  for (int j = 0; j < 16; ++j) {
    int i = tid * 16 + j;
    u16 v = probe[i];
    int e = (v >> 7) & 0xFF;
    if (((i & 1) == 0) && v == 0) zeros++;
    if (e >= 0x8C) huge++;
  }
  sz[tid] = zeros; sh[tid] = huge;
  __syncthreads();
  for (int s = 128; s > 0; s >>= 1) {
    if (tid < s) { sz[tid] += sz[tid + s]; sh[tid] += sh[tid + s]; }
    __syncthreads();
  }
  if (tid == 0) *flag = (sz[0] > 1024 || sh[0] > 200) ? 1 : 0;
}

// ---------------- convert x (4M elems) to bf16 ----------------
__global__ __launch_bounds__(256) void convert_x_kernel(const void* __restrict__ src,
                                                        u16* __restrict__ dst,
                                                        const int* __restrict__ flag) {
  int i = (blockIdx.x * 256 + threadIdx.x) * 4;
  if (*flag) {
    float4 f = *(const float4*)((const float*)src + i);
    u16 o[4] = {f2bf(f.x), f2bf(f.y), f2bf(f.z), f2bf(f.w)};
    *(uint2*)(dst + i) = *(const uint2*)o;
  } else {
    *(uint2*)(dst + i) = *(const uint2*)((const u16*)src + i);
  }
}

// ---------------- convert biases + u + v to fp32 params ----------------
struct ParamPtrs { const void* p[7]; };
__global__ __launch_bounds__(256) void convert_params_kernel(ParamPtrs pp,
                                                             float* __restrict__ pf,
                                                             const int* __restrict__ flag) {
  int idx = blockIdx.x * 256 + threadIdx.x;  // 7168 total
  int seg = idx >> 10, off = idx & 1023;
  const void* s = pp.p[seg];
  pf[idx] = (*flag) ? ((const float*)s)[off] : bf2f(((const u16*)s)[off]);
}

// ---------------- sinusoid position embedding [SEQ, DM] (bf16) ----------------
__global__ __launch_bounds__(256) void sinusoid_kernel(u16* __restrict__ out) {
  int idx = blockIdx.x * 256 + threadIdx.x;
  int s = idx >> 10;
  int i = idx & 1023;
  int j = i & 511;
  float invf = __expf(-(float)j * (9.210340371976184f / 512.0f));
  float ang = (float)s * invf;
  float val = (i < 512) ? sinf(ang) : cosf(ang);
  out[idx] = f2bf(val);
}

// ---------------- transpose + convert the five 1024x1024 weights ----------------
__global__ __launch_bounds__(256) void transpose5_kernel(
    const void* __restrict__ w0, const void* __restrict__ w1,
    const void* __restrict__ w2, const void* __restrict__ w3,
    const void* __restrict__ w4, u16* __restrict__ dst,
    const int* __restrict__ flag) {
  __shared__ u16 t[64][72];
  int z = blockIdx.z;
  const void* src = (z == 0) ? w0 : (z == 1) ? w1 : (z == 2) ? w2 : (z == 3) ? w3 : w4;
  u16* out = dst + (size_t)z * DM * DM;
  int r0 = blockIdx.y * 64, c0 = blockIdx.x * 64;
  int tr = threadIdx.x >> 2;
  int tc = (threadIdx.x & 3) * 16;
  if (*flag) {
    const float* g = (const float*)src + (size_t)(r0 + tr) * DM + c0 + tc;
#pragma unroll
    for (int q = 0; q < 4; ++q) {
      float4 f = *(const float4*)(g + q * 4);
      t[tr][tc + q * 4 + 0] = f2bf(f.x);
      t[tr][tc + q * 4 + 1] = f2bf(f.y);
      t[tr][tc + q * 4 + 2] = f2bf(f.z);
      t[tr][tc + q * 4 + 3] = f2bf(f.w);
    }
  } else {
    const uint4* g = (const uint4*)((const u16*)src + (size_t)(r0 + tr) * DM + c0 + tc);
    uint4 a = g[0], bb = g[1];
    *(uint4*)&t[tr][tc] = a;
    *(uint4*)&t[tr][tc + 8] = bb;
  }
  __syncthreads();
  u16 tmp[16] __attribute__((aligned(16)));
#pragma unroll
  for (int jj = 0; jj < 16; ++jj) tmp[jj] = t[tc + jj][tr];
  uint4* o = (uint4*)(out + (size_t)(c0 + tr) * DM + r0 + tc);
  o[0] = *(const uint4*)&tmp[0];
  o[1] = *(const uint4*)&tmp[8];
}

// ---------------- transpose V [B,S,H,P] -> Vt [B,H,P,S] ----------------
__global__ __launch_bounds__(256) void transpose_v_kernel(
    const u16* __restrict__ V, u16* __restrict__ Vt) {
  __shared__ u16 t[64][72];
  int s0 = blockIdx.x * 64;
  int bh = blockIdx.y;
  int b = bh >> 4, h = bh & 15;
  int tr = threadIdx.x >> 2;
  int tc = (threadIdx.x & 3) * 16;
  const uint4* g = (const uint4*)(V + ((size_t)(b * SEQ + s0 + tr) * NH + h) * PD + tc);
  uint4 a = g[0], bb = g[1];
  *(uint4*)&t[tr][tc] = a;
  *(uint4*)&t[tr][tc + 8] = bb;
  __syncthreads();
  u16 tmp[16] __attribute__((aligned(16)));
#pragma unroll
  for (int jj = 0; jj < 16; ++jj) tmp[jj] = t[tc + jj][tr];
  uint4* o = (uint4*)(Vt + ((size_t)(b * NH + h) * PD + tr) * SEQ + s0 + tc);
  o[0] = *(const uint4*)&tmp[0];
  o[1] = *(const uint4*)&tmp[8];
}

// ---------------- bf16 GEMM v2: global_load_lds staging, m97 2-barrier K-loop ----------------
// z selects among 4 (A, Bt, bias, C) tuples; z==3 may use alternate A with row limit M3.
struct GemmArgs {
  const u16* A;  const u16* A3;
  const u16* Bt0; const u16* Bt1; const u16* Bt2; const u16* Bt3;
  const float* b0; const float* b1; const float* b2; const float* b3;
  void* C0; void* C1; void* C2; void* C3;
  int N, K, M3;
  const int* flag; int outFp32;
};

__global__ __launch_bounds__(256) void gemm_bt_kernel(GemmArgs p) {
  __shared__ u16 As[128 * 32];
  __shared__ u16 Bs[128 * 32];
  int z = blockIdx.z;
  if (z == 3 && (int)blockIdx.y * 128 >= p.M3) return;
  const u16* A = (z == 3) ? p.A3 : p.A;
  const u16* Bt = (z == 0) ? p.Bt0 : (z == 1) ? p.Bt1 : (z == 2) ? p.Bt2 : p.Bt3;
  const float* bias = (z == 0) ? p.b0 : (z == 1) ? p.b1 : (z == 2) ? p.b2 : p.b3;
  void* Cv = (z == 0) ? p.C0 : (z == 1) ? p.C1 : (z == 2) ? p.C2 : p.C3;
  int K = p.K, N = p.N;
  bool f32o = p.outFp32 && (*p.flag);

  int tid = threadIdx.x;
  int wave = tid >> 6, lane = tid & 63;
  int quad = lane >> 4, l16 = lane & 15;
  int m0 = blockIdx.y * 128, n0 = blockIdx.x * 128;
  int wm = (wave >> 1) * 64, wn = (wave & 1) * 64;

  // staging: thread -> tile row (tid>>2) (+64 for round 1), col8 (tid&3)*8
  int trow = tid >> 2;
  int tcol = (tid & 3) * 8;
  const u16* ga = A + (size_t)(m0 + trow) * K + tcol;
  const u16* gb = Bt + (size_t)(n0 + trow) * K + tcol;
  u16* lwa = As + wave * 512;  // wave-uniform base (wave*1024 bytes)
  u16* lwb = Bs + wave * 512;

  f32x4 acc[4][4] = {};

  for (int k0 = 0; k0 < K; k0 += 32) {
    __syncthreads();  // prev frag reads done
    gld16(ga + k0, lwa);
    gld16(ga + (size_t)64 * K + k0, lwa + 2048);
    gld16(gb + k0, lwb);
    gld16(gb + (size_t)64 * K + k0, lwb + 2048);
    __syncthreads();  // tiles landed (vmcnt drained at barrier)
    bf16x8 af[4], bfv[4];
#pragma unroll
    for (int i = 0; i < 4; ++i) {
      af[i] = *(const bf16x8*)&As[(wm + i * 16 + l16) * 32 + quad * 8];
      bfv[i] = *(const bf16x8*)&Bs[(wn + i * 16 + l16) * 32 + quad * 8];
    }
#pragma unroll
    for (int tm = 0; tm < 4; ++tm)
#pragma unroll
      for (int tn = 0; tn < 4; ++tn)
        acc[tm][tn] = __builtin_amdgcn_mfma_f32_16x16x32_bf16(af[tm], bfv[tn], acc[tm][tn], 0, 0, 0);
  }

#pragma unroll
  for (int tm = 0; tm < 4; ++tm) {
    int row = m0 + wm + tm * 16 + quad * 4;
#pragma unroll
    for (int tn = 0; tn < 4; ++tn) {
      int col = n0 + wn + tn * 16 + l16;
      float bv = bias[col];
#pragma unroll
      for (int r = 0; r < 4; ++r) {
        float val = acc[tm][tn][r] + bv;
        if (f32o) ((float*)Cv)[(size_t)(row + r) * N + col] = val;
        else ((u16*)Cv)[(size_t)(row + r) * N + col] = f2bf(val);
      }
    }
  }
}

// ---------------- fused rel-attention v3 ----------------
// Blocked LDS tiles [4 k-blocks][64 rows][16], staged via global_load_lds.
// Pos band: single 64-row transposed slice + per-slice predicated gather.
// P overlays K buffer flat [64][64], quad-rotated column stores (conflict-free).
// 1/8 softmax scale folded into Q prologue (exact pow2).
__global__ __launch_bounds__(256, 4) void attn_kernel(
    const u16* __restrict__ Q, const u16* __restrict__ Kg,
    const u16* __restrict__ Vtg, const u16* __restrict__ Rg,
    const float* __restrict__ pf,
    u16* __restrict__ O) {
  __shared__ __align__(16) u16 KP[4096];    // K blocked / P flat [64][64]
  __shared__ __align__(16) u16 RVs[4096];   // R slice blocked / V blocked (rows = p)
  __shared__ __align__(16) u16 BbT[64 * 66];  // band slice transposed [row][s_local]

  int tid = threadIdx.x, wave = tid >> 6, lane = tid & 63;
  int quad = lane >> 4, l16 = lane & 15;
  int s0 = blockIdx.x * 64;
  int bh = blockIdx.y, b = bh >> 4, h = bh & 15;
  const float* pu = pf + 5 * 1024 + h * PD;
  const float* pv = pf + 6 * 1024 + h * PD;

  int arow = wave * 16 + l16;          // this lane's A-frag row
  int sl_base = wave * 16 + quad * 4;  // C-layout row base

  // staging geometry (shared by K/V/R)
  int srow = (tid >> 1) & 63;
  int scb = tid >> 7;              // 0..1 (round adds +2)
  int sho = (tid & 1) * 8;
  int scol0 = scb * 16 + sho;
  int scol1 = (scb + 2) * 16 + sho;
  u16* kbase = KP + wave * 512;
  u16* rvbase = RVs + wave * 512;
  // fragment-read offset into blocked tiles for k-slot quad*8 (+2048 u16 for k+32)
  int kb0 = (quad >> 1) * 1024 + (quad & 1) * 8 + l16 * 16;

  // ---- prologue: Q fragments in registers, pre-scaled by 1/8 ----
  bf16x8 qu0, qu1, qv0a, qv1a, qv0b, qv1b;
  {
    const u16* qp = Q + ((size_t)(b * SEQ + s0 + arow)) * DM + h * PD;
    int row2 = s0 + arow + 1;
    if (row2 > SEQ - 1) row2 = SEQ - 1;  // clamped row feeds only masked elements
    const u16* qp2 = Q + ((size_t)(b * SEQ + row2)) * DM + h * PD;
    u16 qa[16] __attribute__((aligned(16)));
    u16 qb[16] __attribute__((aligned(16)));
    *(uint4*)&qa[0] = *(const uint4*)(qp + quad * 8);
    *(uint4*)&qa[8] = *(const uint4*)(qp + 32 + quad * 8);
    *(uint4*)&qb[0] = *(const uint4*)(qp2 + quad * 8);
    *(uint4*)&qb[8] = *(const uint4*)(qp2 + 32 + quad * 8);
    u16 fu[16] __attribute__((aligned(16)));
    u16 fv0[16] __attribute__((aligned(16)));
    u16 fv1[16] __attribute__((aligned(16)));
#pragma unroll
    for (int j = 0; j < 8; ++j) {
      float u0 = pu[quad * 8 + j], u1 = pu[32 + quad * 8 + j];
      float v0 = pv[quad * 8 + j], v1 = pv[32 + quad * 8 + j];
      fu[j] = f2bf((bf2f(qa[j]) + u0) * 0.125f);
      fu[8 + j] = f2bf((bf2f(qa[8 + j]) + u1) * 0.125f);
      fv0[j] = f2bf((bf2f(qa[j]) + v0) * 0.125f);
      fv0[8 + j] = f2bf((bf2f(qa[8 + j]) + v1) * 0.125f);
      fv1[j] = f2bf((bf2f(qb[j]) + v0) * 0.125f);
      fv1[8 + j] = f2bf((bf2f(qb[8 + j]) + v1) * 0.125f);
    }
    __builtin_memcpy(&qu0, &fu[0], 16);
    __builtin_memcpy(&qu1, &fu[8], 16);
    __builtin_memcpy(&qv0a, &fv0[0], 16);
    __builtin_memcpy(&qv1a, &fv0[8], 16);
    __builtin_memcpy(&qv0b, &fv1[0], 16);
    __builtin_memcpy(&qv1b, &fv1[8], 16);
  }

  float m_i[4], l_i[4];
#pragma unroll
  for (int r = 0; r < 4; ++r) { m_i[r] = -1e30f; l_i[r] = 0.f; }
  f32x4 oacc[4] = {};

  for (int j0 = 0; j0 < SEQ; j0 += 64) {
    __syncthreads();  // prev PV reads (KP=P, RVs=V) done
    {
      const u16* gk = Kg + (size_t)(b * SEQ + j0 + srow) * DM + h * PD;
      gld16(gk + scol0, kbase);
      gld16(gk + scol1, kbase + 2048);
    }
    __syncthreads();  // K landed

    // content scores -> C-layout registers
    f32x4 acc[4];
#pragma unroll
    for (int tn = 0; tn < 4; ++tn) {
      f32x4 a = {};
      bf16x8 b0 = *(const bf16x8*)&KP[kb0 + tn * 256];
      bf16x8 b1 = *(const bf16x8*)&KP[kb0 + 2048 + tn * 256];
      a = __builtin_amdgcn_mfma_f32_16x16x32_bf16(qu0, b0, a, 0, 0, 0);
      a = __builtin_amdgcn_mfma_f32_16x16x32_bf16(qu1, b1, a, 0, 0, 0);
      acc[tn] = a;
    }

    // positional passes
#pragma unroll 1
    for (int p = 0; p < 2; ++p) {
      int bstart = ((p == 0) ? (SEQ - 65) : -65) + j0 - s0;
      bool act0 = (bstart < SEQ) && (bstart + 64 > 0);
      bool act1 = (bstart + 64 < SEQ) && (bstart + 128 > 0);
      if (!act0 && !act1) continue;
      int thresh = ((p == 0) ? 64 : 65) + s0 - j0;
      int base_t = (p == 0) ? 64 : 63;
      bf16x8 pa0 = (p == 0) ? qv0a : qv0b;
      bf16x8 pa1 = (p == 0) ? qv1a : qv1b;
#pragma unroll 1
      for (int hf = 0; hf < 2; ++hf) {
        bool act = hf ? act1 : act0;
        if (!act) continue;
        int tb0 = bstart + hf * 64;
        bool edge = (tb0 < 0) || (tb0 > SEQ - 64);
        if (edge) {
          uint4 zz = make_uint4(0, 0, 0, 0);
          *(uint4*)(RVs + tid * 8) = zz;
          *(uint4*)(RVs + 2048 + tid * 8) = zz;
          __syncthreads();  // zeros visible before DMA issues
        }
        {
          int tg = tb0 + srow;
          if ((u32)tg < (u32)SEQ) {
            const u16* gr = Rg + (size_t)tg * DM + h * PD;
            gld16(gr + scol0, rvbase);
            gld16(gr + scol1, rvbase + 2048);
          }
        }
        __syncthreads();  // R landed
#pragma unroll
        for (int tt = 0; tt < 4; ++tt) {
          f32x4 pacc = {};
          bf16x8 b0 = *(const bf16x8*)&RVs[kb0 + tt * 256];
          bf16x8 b1 = *(const bf16x8*)&RVs[kb0 + 2048 + tt * 256];
          pacc = __builtin_amdgcn_mfma_f32_16x16x32_bf16(pa0, b0, pacc, 0, 0, 0);
          pacc = __builtin_amdgcn_mfma_f32_16x16x32_bf16(pa1, b1, pacc, 0, 0, 0);
          int rloc = tt * 16 + l16;
          int tbg = hf * 64 + rloc;
          bool val = (p == 0) ? (tbg <= thresh) : (tbg >= thresh);
          u32 w0 = val ? pack2(pacc[0], pacc[1]) : 0u;
          u32 w1 = val ? pack2(pacc[2], pacc[3]) : 0u;
          *(u32*)&BbT[rloc * 66 + sl_base] = w0;
          *(u32*)&BbT[rloc * 66 + sl_base + 2] = w1;
        }
        __syncthreads();  // band stores visible
        // per-slice predicated gather-add
        int Cc = base_t - hf * 64;
#pragma unroll
        for (int tn = 0; tn < 4; ++tn) {
          int rt = Cc + tn * 16 + l16 - sl_base;
#pragma unroll
          for (int r = 0; r < 4; ++r) {
            int rr = rt - r;
            float v = bf2f(BbT[(rr & 63) * 66 + sl_base + r]);
            if ((u32)rr < 64u) acc[tn][r] += v;
          }
        }
      }
    }

    // issue V DMA (overlaps softmax VALU); RVs reads are all complete
    {
      const u16* gv = Vtg + ((size_t)(b * NH + h) * PD + srow) * SEQ + j0;
      gld16(gv + scol0, rvbase);
      gld16(gv + scol1, rvbase + 2048);
    }

    // softmax in C-layout registers (scores already /8)
    float alpha_r[4];
#pragma unroll
    for (int r = 0; r < 4; ++r) {
      float v0 = acc[0][r], v1 = acc[1][r];
      float v2 = acc[2][r], v3 = acc[3][r];
      float mx = fmaxf(fmaxf(v0, v1), fmaxf(v2, v3));
      mx = rmax16(mx);
      float m_new = fmaxf(m_i[r], mx);
      float al = __expf(m_i[r] - m_new);
      u32 w0 = pack2(__expf(v0 - m_new), __expf(v1 - m_new));
      u32 w1 = pack2(__expf(v2 - m_new), __expf(v3 - m_new));
      u16 ec[4] = {(u16)w0, (u16)(w0 >> 16), (u16)w1, (u16)(w1 >> 16)};
      int row = sl_base + r;
      u16* prow_ = KP + row * 64 + l16;
#pragma unroll
      for (int cr = 0; cr < 4; ++cr) {
        int c = (cr + quad) & 3;  // quad-rotated column order: conflict-free banks
        prow_[c * 16] = ec[c];
      }
      float ssum = u2f(w0 << 16) + u2f(w0 & 0xffff0000u) + u2f(w1 << 16) + u2f(w1 & 0xffff0000u);
      ssum = rsum16(ssum);
      l_i[r] = l_i[r] * al + ssum;
      m_i[r] = m_new;
      alpha_r[r] = al;
    }
    __syncthreads();  // V landed + P visible

    // PV
    {
      bf16x8 pa0 = *(const bf16x8*)&KP[arow * 64 + quad * 8];
      bf16x8 pa1 = *(const bf16x8*)&KP[arow * 64 + 32 + quad * 8];
#pragma unroll
      for (int tp = 0; tp < 4; ++tp) {
#pragma unroll
        for (int r = 0; r < 4; ++r) oacc[tp][r] *= alpha_r[r];
        bf16x8 b0 = *(const bf16x8*)&RVs[kb0 + tp * 256];
        bf16x8 b1 = *(const bf16x8*)&RVs[kb0 + 2048 + tp * 256];
        oacc[tp] = __builtin_amdgcn_mfma_f32_16x16x32_bf16(pa0, b0, oacc[tp], 0, 0, 0);
        oacc[tp] = __builtin_amdgcn_mfma_f32_16x16x32_bf16(pa1, b1, oacc[tp], 0, 0, 0);
      }
    }
  }

  // epilogue
#pragma unroll
  for (int r = 0; r < 4; ++r) l_i[r] = 1.f / l_i[r];
#pragma unroll
  for (int tp = 0; tp < 4; ++tp) {
    int pcol = tp * 16 + l16;
#pragma unroll
    for (int r = 0; r < 4; ++r) {
      int sg = s0 + sl_base + r;
      O[((size_t)(b * SEQ + sg)) * DM + h * PD + pcol] = f2bf(oacc[tp][r] * l_i[r]);
    }
  }
}

extern "C" void kernel_launch(void* const* d_in, const int* in_sizes, int n_in,
                              void* d_out, int out_size, void* d_ws, size_t ws_size,
                              hipStream_t stream) {
  (void)in_sizes; (void)n_in; (void)out_size; (void)ws_size;
  const void* x  = d_in[0];
  const void* Wq = d_in[1];
  const void* bq = d_in[2];
  const void* Wk = d_in[3];
  const void* bk = d_in[4];
  const void* Wv = d_in[5];
  const void* bv = d_in[6];
  const void* Wp = d_in[7];
  const void* bp = d_in[8];
  const void* Wo = d_in[9];
  const void* bo = d_in[10];
  const void* u  = d_in[11];
  const void* v  = d_in[12];

  char* base = (char*)d_ws;
  int* flag = (int*)base;
  float* pf = (float*)(base + 64);                       // 7168 floats
  u16* wbase = (u16*)(base + 64 + 7168 * 4);
  u16* WT   = wbase;                                     // 5M elems
  u16* xb   = WT + (size_t)5 * DM * DM;                  // 4M (aliased: Vtb)
  u16* sinb = xb + (size_t)2 * SEQ * DM;                 // 2M
  u16* Qb   = sinb + (size_t)SEQ * DM;                   // 4M
  u16* Kb   = Qb + (size_t)2 * SEQ * DM;                 // 4M
  u16* Vb   = Kb + (size_t)2 * SEQ * DM;                 // 4M (aliased: attn out)
  u16* Rb   = Vb + (size_t)2 * SEQ * DM;                 // 2M
  u16* Vtb  = xb;   // x consumed by QKV gemm before transpose_v writes here
  u16* Ab   = Vb;   // V consumed by transpose_v before attention writes here

  detect_kernel<<<1, 256, 0, stream>>>((const u16*)Wq, flag);

  convert_x_kernel<<<(2 * SEQ * DM) / 1024, 256, 0, stream>>>(x, xb, flag);
  ParamPtrs pp;
  pp.p[0] = bq; pp.p[1] = bk; pp.p[2] = bv; pp.p[3] = bp; pp.p[4] = bo;
  pp.p[5] = u;  pp.p[6] = v;
  convert_params_kernel<<<28, 256, 0, stream>>>(pp, pf, flag);

  sinusoid_kernel<<<(SEQ * DM) / 256, 256, 0, stream>>>(sinb);
  transpose5_kernel<<<dim3(16, 16, 5), 256, 0, stream>>>(Wq, Wk, Wv, Wp, Wo, WT, flag);

  // fused QKV + positional-projection GEMM (z = 0..2: x @ {Wq,Wk,Wv}; z = 3: sin @ Wp)
  GemmArgs qkv;
  qkv.A = xb; qkv.A3 = sinb;
  qkv.Bt0 = WT; qkv.Bt1 = WT + (size_t)DM * DM; qkv.Bt2 = WT + (size_t)2 * DM * DM;
  qkv.Bt3 = WT + (size_t)3 * DM * DM;
  qkv.b0 = pf; qkv.b1 = pf + 1024; qkv.b2 = pf + 2048; qkv.b3 = pf + 3072;
  qkv.C0 = Qb; qkv.C1 = Kb; qkv.C2 = Vb; qkv.C3 = Rb;
  qkv.N = DM; qkv.K = DM; qkv.M3 = SEQ; qkv.flag = flag; qkv.outFp32 = 0;
  gemm_bt_kernel<<<dim3(8, 32, 4), 256, 0, stream>>>(qkv);

  transpose_v_kernel<<<dim3(32, 32), 256, 0, stream>>>(Vb, Vtb);
  attn_kernel<<<dim3(32, 32), 256, 0, stream>>>(Qb, Kb, Vtb, Rb, pf, Ab);

  GemmArgs fo;
  fo.A = Ab; fo.A3 = Ab;
  fo.Bt0 = WT + (size_t)4 * DM * DM; fo.Bt1 = fo.Bt0; fo.Bt2 = fo.Bt0; fo.Bt3 = fo.Bt0;
  fo.b0 = pf + 4096; fo.b1 = fo.b0; fo.b2 = fo.b0; fo.b3 = fo.b0;
  fo.C0 = d_out; fo.C1 = d_out; fo.C2 = d_out; fo.C3 = d_out;
  fo.N = DM; fo.K = DM; fo.M3 = 0; fo.flag = flag; fo.outFp32 = 1;
  gemm_bt_kernel<<<dim3(8, 32, 1), 256, 0, stream>>>(fo);
}

// Round 6
// 427.942 us; speedup vs baseline: 1.0396x; 1.0396x over previous
//
#include <hip/hip_runtime.h>
#include <hip/hip_bf16.h>

typedef unsigned short u16;
typedef unsigned int u32;
typedef __bf16 bf16x8 __attribute__((ext_vector_type(8)));
typedef float f32x4 __attribute__((ext_vector_type(4)));

#define SEQ 2048
#define NH 16
#define PD 64
#define DM 1024

__device__ __forceinline__ float bf2f(u16 s) {
  u32 t = ((u32)s) << 16;
  float f;
  __builtin_memcpy(&f, &t, 4);
  return f;
}
__device__ __forceinline__ u16 f2bf(float f) {
  u32 x;
  __builtin_memcpy(&x, &f, 4);
  x = (x + 0x7fffu + ((x >> 16) & 1u)) >> 16;
  return (u16)x;
}
__device__ __forceinline__ float u2f(u32 b) {
  float f;
  __builtin_memcpy(&f, &b, 4);
  return f;
}
__device__ __forceinline__ u32 pack2(float a, float b) {
  __hip_bfloat162 h = __float22bfloat162_rn(float2{a, b});
  u32 r;
  __builtin_memcpy(&r, &h, 4);
  return r;
}
template <int C>
__device__ __forceinline__ float dppf(float x) {
  int xi;
  __builtin_memcpy(&xi, &x, 4);
  int yi = __builtin_amdgcn_mov_dpp(xi, C, 0xF, 0xF, false);
  float y;
  __builtin_memcpy(&y, &yi, 4);
  return y;
}
__device__ __forceinline__ float rmax16(float x) {
  x = fmaxf(x, dppf<0x121>(x));
  x = fmaxf(x, dppf<0x122>(x));
  x = fmaxf(x, dppf<0x124>(x));
  x = fmaxf(x, dppf<0x128>(x));
  return x;
}
__device__ __forceinline__ float rsum16(float x) {
  x += dppf<0x121>(x);
  x += dppf<0x122>(x);
  x += dppf<0x124>(x);
  x += dppf<0x128>(x);
  return x;
}
// async global -> LDS, 16B per lane. lds dest = wave-uniform base + lane*16B.
__device__ __forceinline__ void gld16(const u16* g, u16* l) {
  __builtin_amdgcn_global_load_lds(
      (const __attribute__((address_space(1))) unsigned int*)(g),
      (__attribute__((address_space(3))) unsigned int*)(l), 16, 0, 0);
}

// ---------------- dtype detection (fp32 vs bf16 input buffers) ----------------
__global__ __launch_bounds__(256) void detect_kernel(const u16* __restrict__ probe,
                                                     int* __restrict__ flag) {
  __shared__ int sz[256], sh[256];
  int tid = threadIdx.x;
  int zeros = 0, huge = 0;
  for (int j = 0; j < 16; ++j) {
    int i = tid * 16 + j;
    u16 v = probe[i];
    int e = (v >> 7) & 0xFF;
    if (((i & 1) == 0) && v == 0) zeros++;
    if (e >= 0x8C) huge++;
  }
  sz[tid] = zeros; sh[tid] = huge;
  __syncthreads();
  for (int s = 128; s > 0; s >>= 1) {
    if (tid < s) { sz[tid] += sz[tid + s]; sh[tid] += sh[tid + s]; }
    __syncthreads();
  }
  if (tid == 0) *flag = (sz[0] > 1024 || sh[0] > 200) ? 1 : 0;
}

// ---------------- convert x (4M elems) to bf16 ----------------
__global__ __launch_bounds__(256) void convert_x_kernel(const void* __restrict__ src,
                                                        u16* __restrict__ dst,
                                                        const int* __restrict__ flag) {
  int i = (blockIdx.x * 256 + threadIdx.x) * 4;
  if (*flag) {
    float4 f = *(const float4*)((const float*)src + i);
    u16 o[4] = {f2bf(f.x), f2bf(f.y), f2bf(f.z), f2bf(f.w)};
    *(uint2*)(dst + i) = *(const uint2*)o;
  } else {
    *(uint2*)(dst + i) = *(const uint2*)((const u16*)src + i);
  }
}

// ---------------- convert biases + u + v to fp32 params ----------------
struct ParamPtrs { const void* p[7]; };
__global__ __launch_bounds__(256) void convert_params_kernel(ParamPtrs pp,
                                                             float* __restrict__ pf,
                                                             const int* __restrict__ flag) {
  int idx = blockIdx.x * 256 + threadIdx.x;  // 7168 total
  int seg = idx >> 10, off = idx & 1023;
  const void* s = pp.p[seg];
  pf[idx] = (*flag) ? ((const float*)s)[off] : bf2f(((const u16*)s)[off]);
}

// ---------------- sinusoid position embedding [SEQ, DM] (bf16) ----------------
__global__ __launch_bounds__(256) void sinusoid_kernel(u16* __restrict__ out) {
  int idx = blockIdx.x * 256 + threadIdx.x;
  int s = idx >> 10;
  int i = idx & 1023;
  int j = i & 511;
  float invf = __expf(-(float)j * (9.210340371976184f / 512.0f));
  float ang = (float)s * invf;
  float val = (i < 512) ? sinf(ang) : cosf(ang);
  out[idx] = f2bf(val);
}

// ---------------- transpose + convert the five 1024x1024 weights ----------------
__global__ __launch_bounds__(256) void transpose5_kernel(
    const void* __restrict__ w0, const void* __restrict__ w1,
    const void* __restrict__ w2, const void* __restrict__ w3,
    const void* __restrict__ w4, u16* __restrict__ dst,
    const int* __restrict__ flag) {
  __shared__ u16 t[64][72];
  int z = blockIdx.z;
  const void* src = (z == 0) ? w0 : (z == 1) ? w1 : (z == 2) ? w2 : (z == 3) ? w3 : w4;
  u16* out = dst + (size_t)z * DM * DM;
  int r0 = blockIdx.y * 64, c0 = blockIdx.x * 64;
  int tr = threadIdx.x >> 2;
  int tc = (threadIdx.x & 3) * 16;
  if (*flag) {
    const float* g = (const float*)src + (size_t)(r0 + tr) * DM + c0 + tc;
#pragma unroll
    for (int q = 0; q < 4; ++q) {
      float4 f = *(const float4*)(g + q * 4);
      t[tr][tc + q * 4 + 0] = f2bf(f.x);
      t[tr][tc + q * 4 + 1] = f2bf(f.y);
      t[tr][tc + q * 4 + 2] = f2bf(f.z);
      t[tr][tc + q * 4 + 3] = f2bf(f.w);
    }
  } else {
    const uint4* g = (const uint4*)((const u16*)src + (size_t)(r0 + tr) * DM + c0 + tc);
    uint4 a = g[0], bb = g[1];
    *(uint4*)&t[tr][tc] = a;
    *(uint4*)&t[tr][tc + 8] = bb;
  }
  __syncthreads();
  u16 tmp[16] __attribute__((aligned(16)));
#pragma unroll
  for (int jj = 0; jj < 16; ++jj) tmp[jj] = t[tc + jj][tr];
  uint4* o = (uint4*)(out + (size_t)(c0 + tr) * DM + r0 + tc);
  o[0] = *(const uint4*)&tmp[0];
  o[1] = *(const uint4*)&tmp[8];
}

// ---------------- transpose V [B,S,H,P] -> Vt [B,H,P,S] ----------------
__global__ __launch_bounds__(256) void transpose_v_kernel(
    const u16* __restrict__ V, u16* __restrict__ Vt) {
  __shared__ u16 t[64][72];
  int s0 = blockIdx.x * 64;
  int bh = blockIdx.y;
  int b = bh >> 4, h = bh & 15;
  int tr = threadIdx.x >> 2;
  int tc = (threadIdx.x & 3) * 16;
  const uint4* g = (const uint4*)(V + ((size_t)(b * SEQ + s0 + tr) * NH + h) * PD + tc);
  uint4 a = g[0], bb = g[1];
  *(uint4*)&t[tr][tc] = a;
  *(uint4*)&t[tr][tc + 8] = bb;
  __syncthreads();
  u16 tmp[16] __attribute__((aligned(16)));
#pragma unroll
  for (int jj = 0; jj < 16; ++jj) tmp[jj] = t[tc + jj][tr];
  uint4* o = (uint4*)(Vt + ((size_t)(b * NH + h) * PD + tr) * SEQ + s0 + tc);
  o[0] = *(const uint4*)&tmp[0];
  o[1] = *(const uint4*)&tmp[8];
}

// ---------------- bf16 GEMM: global_load_lds staging, m97 2-barrier K-loop ----------------
struct GemmArgs {
  const u16* A;  const u16* A3;
  const u16* Bt0; const u16* Bt1; const u16* Bt2; const u16* Bt3;
  const float* b0; const float* b1; const float* b2; const float* b3;
  void* C0; void* C1; void* C2; void* C3;
  int N, K, M3;
  const int* flag; int outFp32;
};

__global__ __launch_bounds__(256, 4) void gemm_bt_kernel(GemmArgs p) {
  __shared__ u16 As[128 * 32];
  __shared__ u16 Bs[128 * 32];
  int z = blockIdx.z;
  if (z == 3 && (int)blockIdx.y * 128 >= p.M3) return;
  const u16* A = (z == 3) ? p.A3 : p.A;
  const u16* Bt = (z == 0) ? p.Bt0 : (z == 1) ? p.Bt1 : (z == 2) ? p.Bt2 : p.Bt3;
  const float* bias = (z == 0) ? p.b0 : (z == 1) ? p.b1 : (z == 2) ? p.b2 : p.b3;
  void* Cv = (z == 0) ? p.C0 : (z == 1) ? p.C1 : (z == 2) ? p.C2 : p.C3;
  int K = p.K, N = p.N;
  bool f32o = p.outFp32 && (*p.flag);

  int tid = threadIdx.x;
  int wave = tid >> 6, lane = tid & 63;
  int quad = lane >> 4, l16 = lane & 15;
  int m0 = blockIdx.y * 128, n0 = blockIdx.x * 128;
  int wm = (wave >> 1) * 64, wn = (wave & 1) * 64;

  int trow = tid >> 2;
  int tcol = (tid & 3) * 8;
  const u16* ga = A + (size_t)(m0 + trow) * K + tcol;
  const u16* gb = Bt + (size_t)(n0 + trow) * K + tcol;
  u16* lwa = As + wave * 512;
  u16* lwb = Bs + wave * 512;

  f32x4 acc[4][4] = {};

  for (int k0 = 0; k0 < K; k0 += 32) {
    __syncthreads();
    gld16(ga + k0, lwa);
    gld16(ga + (size_t)64 * K + k0, lwa + 2048);
    gld16(gb + k0, lwb);
    gld16(gb + (size_t)64 * K + k0, lwb + 2048);
    __syncthreads();
    bf16x8 af[4], bfv[4];
#pragma unroll
    for (int i = 0; i < 4; ++i) {
      af[i] = *(const bf16x8*)&As[(wm + i * 16 + l16) * 32 + quad * 8];
      bfv[i] = *(const bf16x8*)&Bs[(wn + i * 16 + l16) * 32 + quad * 8];
    }
#pragma unroll
    for (int tm = 0; tm < 4; ++tm)
#pragma unroll
      for (int tn = 0; tn < 4; ++tn)
        acc[tm][tn] = __builtin_amdgcn_mfma_f32_16x16x32_bf16(af[tm], bfv[tn], acc[tm][tn], 0, 0, 0);
  }

#pragma unroll
  for (int tm = 0; tm < 4; ++tm) {
    int row = m0 + wm + tm * 16 + quad * 4;
#pragma unroll
    for (int tn = 0; tn < 4; ++tn) {
      int col = n0 + wn + tn * 16 + l16;
      float bv = bias[col];
#pragma unroll
      for (int r = 0; r < 4; ++r) {
        float val = acc[tm][tn][r] + bv;
        if (f32o) ((float*)Cv)[(size_t)(row + r) * N + col] = val;
        else ((u16*)Cv)[(size_t)(row + r) * N + col] = f2bf(val);
      }
    }
  }
}

// ---------------- fused rel-attention v4 ----------------
// XCD-swizzled 1D grid: all q-blocks of one head land on one XCD (L2 locality).
// Full-line DMA staging: row = wave*16 + (lane>>2), col = (lane&3)*8, blocked [2][64][32].
__global__ __launch_bounds__(256, 4) void attn_kernel(
    const u16* __restrict__ Q, const u16* __restrict__ Kg,
    const u16* __restrict__ Vtg, const u16* __restrict__ Rg,
    const float* __restrict__ pf,
    u16* __restrict__ O) {
  __shared__ __align__(16) u16 KP[4096];     // K blocked / P flat [64][64]
  __shared__ __align__(16) u16 RVs[4096];    // R slice blocked / V blocked
  __shared__ __align__(16) u16 BbT[64 * 66]; // band slice transposed [row][s_local]

  int tid = threadIdx.x, wave = tid >> 6, lane = tid & 63;
  int quad = lane >> 4, l16 = lane & 15;
  int id = blockIdx.x;
  int bh = (id & 7) + ((id >> 8) << 3);  // same-head blocks share id%8 -> same XCD
  int s0 = ((id >> 3) & 31) * 64;
  int b = bh >> 4, h = bh & 15;
  const float* pu = pf + 5 * 1024 + h * PD;
  const float* pv = pf + 6 * 1024 + h * PD;

  int arow = wave * 16 + l16;          // this lane's A-frag row
  int sl_base = wave * 16 + quad * 4;  // C-layout row base

  // staging geometry: 4 lanes cover one 64B line; wave covers 16 rows
  int srow = wave * 16 + (lane >> 2);
  int scol = (lane & 3) * 8;
  u16* kbase = KP + wave * 512;
  u16* rvbase = RVs + wave * 512;
  // fragment-read base into blocked [2][64][32] tiles (row l16, k-lo quad*8)
  int kb0 = l16 * 32 + quad * 8;

  // ---- prologue: Q fragments in registers, pre-scaled by 1/8 ----
  bf16x8 qu0, qu1, qv0a, qv1a, qv0b, qv1b;
  {
    const u16* qp = Q + ((size_t)(b * SEQ + s0 + arow)) * DM + h * PD;
    int row2 = s0 + arow + 1;
    if (row2 > SEQ - 1) row2 = SEQ - 1;  // clamped row feeds only masked elements
    const u16* qp2 = Q + ((size_t)(b * SEQ + row2)) * DM + h * PD;
    u16 qa[16] __attribute__((aligned(16)));
    u16 qb[16] __attribute__((aligned(16)));
    *(uint4*)&qa[0] = *(const uint4*)(qp + quad * 8);
    *(uint4*)&qa[8] = *(const uint4*)(qp + 32 + quad * 8);
    *(uint4*)&qb[0] = *(const uint4*)(qp2 + quad * 8);
    *(uint4*)&qb[8] = *(const uint4*)(qp2 + 32 + quad * 8);
    u16 fu[16] __attribute__((aligned(16)));
    u16 fv0[16] __attribute__((aligned(16)));
    u16 fv1[16] __attribute__((aligned(16)));
#pragma unroll
    for (int j = 0; j < 8; ++j) {
      float u0 = pu[quad * 8 + j], u1 = pu[32 + quad * 8 + j];
      float v0 = pv[quad * 8 + j], v1 = pv[32 + quad * 8 + j];
      fu[j] = f2bf((bf2f(qa[j]) + u0) * 0.125f);
      fu[8 + j] = f2bf((bf2f(qa[8 + j]) + u1) * 0.125f);
      fv0[j] = f2bf((bf2f(qa[j]) + v0) * 0.125f);
      fv0[8 + j] = f2bf((bf2f(qa[8 + j]) + v1) * 0.125f);
      fv1[j] = f2bf((bf2f(qb[j]) + v0) * 0.125f);
      fv1[8 + j] = f2bf((bf2f(qb[8 + j]) + v1) * 0.125f);
    }
    __builtin_memcpy(&qu0, &fu[0], 16);
    __builtin_memcpy(&qu1, &fu[8], 16);
    __builtin_memcpy(&qv0a, &fv0[0], 16);
    __builtin_memcpy(&qv1a, &fv0[8], 16);
    __builtin_memcpy(&qv0b, &fv1[0], 16);
    __builtin_memcpy(&qv1b, &fv1[8], 16);
  }

  float m_i[4], l_i[4];
#pragma unroll
  for (int r = 0; r < 4; ++r) { m_i[r] = -1e30f; l_i[r] = 0.f; }
  f32x4 oacc[4] = {};

  for (int j0 = 0; j0 < SEQ; j0 += 64) {
    __syncthreads();  // prev PV reads (KP=P, RVs=V) done
    {
      const u16* gk = Kg + (size_t)(b * SEQ + j0 + srow) * DM + h * PD + scol;
      gld16(gk, kbase);
      gld16(gk + 32, kbase + 2048);
    }
    __syncthreads();  // K landed

    // content scores -> C-layout registers
    f32x4 acc[4];
#pragma unroll
    for (int tn = 0; tn < 4; ++tn) {
      f32x4 a = {};
      bf16x8 b0 = *(const bf16x8*)&KP[kb0 + tn * 512];
      bf16x8 b1 = *(const bf16x8*)&KP[kb0 + tn * 512 + 2048];
      a = __builtin_amdgcn_mfma_f32_16x16x32_bf16(qu0, b0, a, 0, 0, 0);
      a = __builtin_amdgcn_mfma_f32_16x16x32_bf16(qu1, b1, a, 0, 0, 0);
      acc[tn] = a;
    }

    // positional passes
#pragma unroll 1
    for (int p = 0; p < 2; ++p) {
      int bstart = ((p == 0) ? (SEQ - 65) : -65) + j0 - s0;
      bool act0 = (bstart < SEQ) && (bstart + 64 > 0);
      bool act1 = (bstart + 64 < SEQ) && (bstart + 128 > 0);
      if (!act0 && !act1) continue;
      int thresh = ((p == 0) ? 64 : 65) + s0 - j0;
      int base_t = (p == 0) ? 64 : 63;
      bf16x8 pa0 = (p == 0) ? qv0a : qv0b;
      bf16x8 pa1 = (p == 0) ? qv1a : qv1b;
#pragma unroll 1
      for (int hf = 0; hf < 2; ++hf) {
        bool act = hf ? act1 : act0;
        if (!act) continue;
        int tb0 = bstart + hf * 64;
        bool edge = (tb0 < 0) || (tb0 > SEQ - 64);
        if (edge) {
          uint4 zz = make_uint4(0, 0, 0, 0);
          *(uint4*)(RVs + tid * 8) = zz;
          *(uint4*)(RVs + 2048 + tid * 8) = zz;
          __syncthreads();  // zeros visible before DMA issues
        }
        {
          int tg = tb0 + srow;
          if ((u32)tg < (u32)SEQ) {
            const u16* gr = Rg + (size_t)tg * DM + h * PD + scol;
            gld16(gr, rvbase);
            gld16(gr + 32, rvbase + 2048);
          }
        }
        __syncthreads();  // R landed
#pragma unroll
        for (int tt = 0; tt < 4; ++tt) {
          f32x4 pacc = {};
          bf16x8 b0 = *(const bf16x8*)&RVs[kb0 + tt * 512];
          bf16x8 b1 = *(const bf16x8*)&RVs[kb0 + tt * 512 + 2048];
          pacc = __builtin_amdgcn_mfma_f32_16x16x32_bf16(pa0, b0, pacc, 0, 0, 0);
          pacc = __builtin_amdgcn_mfma_f32_16x16x32_bf16(pa1, b1, pacc, 0, 0, 0);
          int rloc = tt * 16 + l16;
          int tbg = hf * 64 + rloc;
          bool val = (p == 0) ? (tbg <= thresh) : (tbg >= thresh);
          u32 w0 = val ? pack2(pacc[0], pacc[1]) : 0u;
          u32 w1 = val ? pack2(pacc[2], pacc[3]) : 0u;
          *(u32*)&BbT[rloc * 66 + sl_base] = w0;
          *(u32*)&BbT[rloc * 66 + sl_base + 2] = w1;
        }
        __syncthreads();  // band stores visible
        // per-slice predicated gather-add
        int Cc = base_t - hf * 64;
#pragma unroll
        for (int tn = 0; tn < 4; ++tn) {
          int rt = Cc + tn * 16 + l16 - sl_base;
#pragma unroll
          for (int r = 0; r < 4; ++r) {
            int rr = rt - r;
            float v = bf2f(BbT[(rr & 63) * 66 + sl_base + r]);
            if ((u32)rr < 64u) acc[tn][r] += v;
          }
        }
      }
    }

    // issue V DMA (drains at the pre-PV barrier); RVs reads are all complete
    {
      const u16* gv = Vtg + ((size_t)(b * NH + h) * PD + srow) * SEQ + j0 + scol;
      gld16(gv, rvbase);
      gld16(gv + 32, rvbase + 2048);
    }

    // softmax in C-layout registers (scores already /8)
    float alpha_r[4];
#pragma unroll
    for (int r = 0; r < 4; ++r) {
      float v0 = acc[0][r], v1 = acc[1][r];
      float v2 = acc[2][r], v3 = acc[3][r];
      float mx = fmaxf(fmaxf(v0, v1), fmaxf(v2, v3));
      mx = rmax16(mx);
      float m_new = fmaxf(m_i[r], mx);
      float al = __expf(m_i[r] - m_new);
      u32 w0 = pack2(__expf(v0 - m_new), __expf(v1 - m_new));
      u32 w1 = pack2(__expf(v2 - m_new), __expf(v3 - m_new));
      u16 ec[4] = {(u16)w0, (u16)(w0 >> 16), (u16)w1, (u16)(w1 >> 16)};
      int row = sl_base + r;
      u16* prow_ = KP + row * 64 + l16;
#pragma unroll
      for (int cr = 0; cr < 4; ++cr) {
        int c = (cr + quad) & 3;  // quad-rotated column order: conflict-free banks
        prow_[c * 16] = ec[c];
      }
      float ssum = u2f(w0 << 16) + u2f(w0 & 0xffff0000u) + u2f(w1 << 16) + u2f(w1 & 0xffff0000u);
      ssum = rsum16(ssum);
      l_i[r] = l_i[r] * al + ssum;
      m_i[r] = m_new;
      alpha_r[r] = al;
    }
    __syncthreads();  // V landed + P visible

    // PV
    {
      bf16x8 pa0 = *(const bf16x8*)&KP[arow * 64 + quad * 8];
      bf16x8 pa1 = *(const bf16x8*)&KP[arow * 64 + 32 + quad * 8];
#pragma unroll
      for (int tp = 0; tp < 4; ++tp) {
#pragma unroll
        for (int r = 0; r < 4; ++r) oacc[tp][r] *= alpha_r[r];
        bf16x8 b0 = *(const bf16x8*)&RVs[kb0 + tp * 512];
        bf16x8 b1 = *(const bf16x8*)&RVs[kb0 + tp * 512 + 2048];
        oacc[tp] = __builtin_amdgcn_mfma_f32_16x16x32_bf16(pa0, b0, oacc[tp], 0, 0, 0);
        oacc[tp] = __builtin_amdgcn_mfma_f32_16x16x32_bf16(pa1, b1, oacc[tp], 0, 0, 0);
      }
    }
  }

  // epilogue
#pragma unroll
  for (int r = 0; r < 4; ++r) l_i[r] = 1.f / l_i[r];
#pragma unroll
  for (int tp = 0; tp < 4; ++tp) {
    int pcol = tp * 16 + l16;
#pragma unroll
    for (int r = 0; r < 4; ++r) {
      int sg = s0 + sl_base + r;
      O[((size_t)(b * SEQ + sg)) * DM + h * PD + pcol] = f2bf(oacc[tp][r] * l_i[r]);
    }
  }
}

extern "C" void kernel_launch(void* const* d_in, const int* in_sizes, int n_in,
                              void* d_out, int out_size, void* d_ws, size_t ws_size,
                              hipStream_t stream) {
  (void)in_sizes; (void)n_in; (void)out_size; (void)ws_size;
  const void* x  = d_in[0];
  const void* Wq = d_in[1];
  const void* bq = d_in[2];
  const void* Wk = d_in[3];
  const void* bk = d_in[4];
  const void* Wv = d_in[5];
  const void* bv = d_in[6];
  const void* Wp = d_in[7];
  const void* bp = d_in[8];
  const void* Wo = d_in[9];
  const void* bo = d_in[10];
  const void* u  = d_in[11];
  const void* v  = d_in[12];

  char* base = (char*)d_ws;
  int* flag = (int*)base;
  float* pf = (float*)(base + 64);                       // 7168 floats
  u16* wbase = (u16*)(base + 64 + 7168 * 4);
  u16* WT   = wbase;                                     // 5M elems
  u16* xb   = WT + (size_t)5 * DM * DM;                  // 4M (aliased: Vtb)
  u16* sinb = xb + (size_t)2 * SEQ * DM;                 // 2M
  u16* Qb   = sinb + (size_t)SEQ * DM;                   // 4M
  u16* Kb   = Qb + (size_t)2 * SEQ * DM;                 // 4M
  u16* Vb   = Kb + (size_t)2 * SEQ * DM;                 // 4M (aliased: attn out)
  u16* Rb   = Vb + (size_t)2 * SEQ * DM;                 // 2M
  u16* Vtb  = xb;   // x consumed by QKV gemm before transpose_v writes here
  u16* Ab   = Vb;   // V consumed by transpose_v before attention writes here

  detect_kernel<<<1, 256, 0, stream>>>((const u16*)Wq, flag);

  convert_x_kernel<<<(2 * SEQ * DM) / 1024, 256, 0, stream>>>(x, xb, flag);
  ParamPtrs pp;
  pp.p[0] = bq; pp.p[1] = bk; pp.p[2] = bv; pp.p[3] = bp; pp.p[4] = bo;
  pp.p[5] = u;  pp.p[6] = v;
  convert_params_kernel<<<28, 256, 0, stream>>>(pp, pf, flag);

  sinusoid_kernel<<<(SEQ * DM) / 256, 256, 0, stream>>>(sinb);
  transpose5_kernel<<<dim3(16, 16, 5), 256, 0, stream>>>(Wq, Wk, Wv, Wp, Wo, WT, flag);

  // fused QKV + positional-projection GEMM (z = 0..2: x @ {Wq,Wk,Wv}; z = 3: sin @ Wp)
  GemmArgs qkv;
  qkv.A = xb; qkv.A3 = sinb;
  qkv.Bt0 = WT; qkv.Bt1 = WT + (size_t)DM * DM; qkv.Bt2 = WT + (size_t)2 * DM * DM;
  qkv.Bt3 = WT + (size_t)3 * DM * DM;
  qkv.b0 = pf; qkv.b1 = pf + 1024; qkv.b2 = pf + 2048; qkv.b3 = pf + 3072;
  qkv.C0 = Qb; qkv.C1 = Kb; qkv.C2 = Vb; qkv.C3 = Rb;
  qkv.N = DM; qkv.K = DM; qkv.M3 = SEQ; qkv.flag = flag; qkv.outFp32 = 0;
  gemm_bt_kernel<<<dim3(8, 32, 4), 256, 0, stream>>>(qkv);

  transpose_v_kernel<<<dim3(32, 32), 256, 0, stream>>>(Vb, Vtb);
  attn_kernel<<<dim3(1024), 256, 0, stream>>>(Qb, Kb, Vtb, Rb, pf, Ab);

  GemmArgs fo;
  fo.A = Ab; fo.A3 = Ab;
  fo.Bt0 = WT + (size_t)4 * DM * DM; fo.Bt1 = fo.Bt0; fo.Bt2 = fo.Bt0; fo.Bt3 = fo.Bt0;
  fo.b0 = pf + 4096; fo.b1 = fo.b0; fo.b2 = fo.b0; fo.b3 = fo.b0;
  fo.C0 = d_out; fo.C1 = d_out; fo.C2 = d_out; fo.C3 = d_out;
  fo.N = DM; fo.K = DM; fo.M3 = 0; fo.flag = flag; fo.outFp32 = 1;
  gemm_bt_kernel<<<dim3(8, 32, 1), 256, 0, stream>>>(fo);
}

// Round 7
// 387.135 us; speedup vs baseline: 1.1492x; 1.1054x over previous
//
#include <hip/hip_runtime.h>
#include <hip/hip_bf16.h>

typedef unsigned short u16;
typedef unsigned int u32;
typedef __bf16 bf16x8 __attribute__((ext_vector_type(8)));
typedef float f32x4 __attribute__((ext_vector_type(4)));

#define SEQ 2048
#define NH 16
#define PD 64
#define DM 1024

__device__ __forceinline__ float bf2f(u16 s) {
  u32 t = ((u32)s) << 16;
  float f;
  __builtin_memcpy(&f, &t, 4);
  return f;
}
__device__ __forceinline__ u16 f2bf(float f) {
  u32 x;
  __builtin_memcpy(&x, &f, 4);
  x = (x + 0x7fffu + ((x >> 16) & 1u)) >> 16;
  return (u16)x;
}
__device__ __forceinline__ float u2f(u32 b) {
  float f;
  __builtin_memcpy(&f, &b, 4);
  return f;
}
__device__ __forceinline__ u32 pack2(float a, float b) {
  __hip_bfloat162 h = __float22bfloat162_rn(float2{a, b});
  u32 r;
  __builtin_memcpy(&r, &h, 4);
  return r;
}
template <int C>
__device__ __forceinline__ float dppf(float x) {
  int xi;
  __builtin_memcpy(&xi, &x, 4);
  int yi = __builtin_amdgcn_mov_dpp(xi, C, 0xF, 0xF, false);
  float y;
  __builtin_memcpy(&y, &yi, 4);
  return y;
}
__device__ __forceinline__ float rmax16(float x) {
  x = fmaxf(x, dppf<0x121>(x));
  x = fmaxf(x, dppf<0x122>(x));
  x = fmaxf(x, dppf<0x124>(x));
  x = fmaxf(x, dppf<0x128>(x));
  return x;
}
__device__ __forceinline__ float rsum16(float x) {
  x += dppf<0x121>(x);
  x += dppf<0x122>(x);
  x += dppf<0x124>(x);
  x += dppf<0x128>(x);
  return x;
}
// async global -> LDS, 16B per lane. lds dest = wave-uniform base + lane*16B.
__device__ __forceinline__ void gld16(const u16* g, u16* l) {
  __builtin_amdgcn_global_load_lds(
      (const __attribute__((address_space(1))) unsigned int*)(g),
      (__attribute__((address_space(3))) unsigned int*)(l), 16, 0, 0);
}

// ---------------- dtype detection (fp32 vs bf16 input buffers) ----------------
__global__ __launch_bounds__(256) void detect_kernel(const u16* __restrict__ probe,
                                                     int* __restrict__ flag) {
  __shared__ int sz[256], sh[256];
  int tid = threadIdx.x;
  int zeros = 0, huge = 0;
  for (int j = 0; j < 16; ++j) {
    int i = tid * 16 + j;
    u16 v = probe[i];
    int e = (v >> 7) & 0xFF;
    if (((i & 1) == 0) && v == 0) zeros++;
    if (e >= 0x8C) huge++;
  }
  sz[tid] = zeros; sh[tid] = huge;
  __syncthreads();
  for (int s = 128; s > 0; s >>= 1) {
    if (tid < s) { sz[tid] += sz[tid + s]; sh[tid] += sh[tid + s]; }
    __syncthreads();
  }
  if (tid == 0) *flag = (sz[0] > 1024 || sh[0] > 200) ? 1 : 0;
}

// ---------------- convert x (4M elems) to bf16 ----------------
__global__ __launch_bounds__(256) void convert_x_kernel(const void* __restrict__ src,
                                                        u16* __restrict__ dst,
                                                        const int* __restrict__ flag) {
  int i = (blockIdx.x * 256 + threadIdx.x) * 4;
  if (*flag) {
    float4 f = *(const float4*)((const float*)src + i);
    u16 o[4] = {f2bf(f.x), f2bf(f.y), f2bf(f.z), f2bf(f.w)};
    *(uint2*)(dst + i) = *(const uint2*)o;
  } else {
    *(uint2*)(dst + i) = *(const uint2*)((const u16*)src + i);
  }
}

// ---------------- convert biases + u + v to fp32 params ----------------
struct ParamPtrs { const void* p[7]; };
__global__ __launch_bounds__(256) void convert_params_kernel(ParamPtrs pp,
                                                             float* __restrict__ pf,
                                                             const int* __restrict__ flag) {
  int idx = blockIdx.x * 256 + threadIdx.x;  // 7168 total
  int seg = idx >> 10, off = idx & 1023;
  const void* s = pp.p[seg];
  pf[idx] = (*flag) ? ((const float*)s)[off] : bf2f(((const u16*)s)[off]);
}

// ---------------- sinusoid position embedding [SEQ, DM] (bf16) ----------------
__global__ __launch_bounds__(256) void sinusoid_kernel(u16* __restrict__ out) {
  int idx = blockIdx.x * 256 + threadIdx.x;
  int s = idx >> 10;
  int i = idx & 1023;
  int j = i & 511;
  float invf = __expf(-(float)j * (9.210340371976184f / 512.0f));
  float ang = (float)s * invf;
  float val = (i < 512) ? sinf(ang) : cosf(ang);
  out[idx] = f2bf(val);
}

// ---------------- transpose + convert the five 1024x1024 weights ----------------
__global__ __launch_bounds__(256) void transpose5_kernel(
    const void* __restrict__ w0, const void* __restrict__ w1,
    const void* __restrict__ w2, const void* __restrict__ w3,
    const void* __restrict__ w4, u16* __restrict__ dst,
    const int* __restrict__ flag) {
  __shared__ u16 t[64][72];
  int z = blockIdx.z;
  const void* src = (z == 0) ? w0 : (z == 1) ? w1 : (z == 2) ? w2 : (z == 3) ? w3 : w4;
  u16* out = dst + (size_t)z * DM * DM;
  int r0 = blockIdx.y * 64, c0 = blockIdx.x * 64;
  int tr = threadIdx.x >> 2;
  int tc = (threadIdx.x & 3) * 16;
  if (*flag) {
    const float* g = (const float*)src + (size_t)(r0 + tr) * DM + c0 + tc;
#pragma unroll
    for (int q = 0; q < 4; ++q) {
      float4 f = *(const float4*)(g + q * 4);
      t[tr][tc + q * 4 + 0] = f2bf(f.x);
      t[tr][tc + q * 4 + 1] = f2bf(f.y);
      t[tr][tc + q * 4 + 2] = f2bf(f.z);
      t[tr][tc + q * 4 + 3] = f2bf(f.w);
    }
  } else {
    const uint4* g = (const uint4*)((const u16*)src + (size_t)(r0 + tr) * DM + c0 + tc);
    uint4 a = g[0], bb = g[1];
    *(uint4*)&t[tr][tc] = a;
    *(uint4*)&t[tr][tc + 8] = bb;
  }
  __syncthreads();
  u16 tmp[16] __attribute__((aligned(16)));
#pragma unroll
  for (int jj = 0; jj < 16; ++jj) tmp[jj] = t[tc + jj][tr];
  uint4* o = (uint4*)(out + (size_t)(c0 + tr) * DM + r0 + tc);
  o[0] = *(const uint4*)&tmp[0];
  o[1] = *(const uint4*)&tmp[8];
}

// ---------------- transpose V [B,S,H,P] -> Vt [B,H,P,S] ----------------
__global__ __launch_bounds__(256) void transpose_v_kernel(
    const u16* __restrict__ V, u16* __restrict__ Vt) {
  __shared__ u16 t[64][72];
  int s0 = blockIdx.x * 64;
  int bh = blockIdx.y;
  int b = bh >> 4, h = bh & 15;
  int tr = threadIdx.x >> 2;
  int tc = (threadIdx.x & 3) * 16;
  const uint4* g = (const uint4*)(V + ((size_t)(b * SEQ + s0 + tr) * NH + h) * PD + tc);
  uint4 a = g[0], bb = g[1];
  *(uint4*)&t[tr][tc] = a;
  *(uint4*)&t[tr][tc + 8] = bb;
  __syncthreads();
  u16 tmp[16] __attribute__((aligned(16)));
#pragma unroll
  for (int jj = 0; jj < 16; ++jj) tmp[jj] = t[tc + jj][tr];
  uint4* o = (uint4*)(Vt + ((size_t)(b * NH + h) * PD + tr) * SEQ + s0 + tc);
  o[0] = *(const uint4*)&tmp[0];
  o[1] = *(const uint4*)&tmp[8];
}

// ---------------- bf16 GEMM: global_load_lds staging, m97 2-barrier K-loop ----------------
struct GemmArgs {
  const u16* A;  const u16* A3;
  const u16* Bt0; const u16* Bt1; const u16* Bt2; const u16* Bt3;
  const float* b0; const float* b1; const float* b2; const float* b3;
  void* C0; void* C1; void* C2; void* C3;
  int N, K, M3;
  const int* flag; int outFp32;
};

__global__ __launch_bounds__(256, 4) void gemm_bt_kernel(GemmArgs p) {
  __shared__ u16 As[128 * 32];
  __shared__ u16 Bs[128 * 32];
  int z = blockIdx.z;
  if (z == 3 && (int)blockIdx.y * 128 >= p.M3) return;
  const u16* A = (z == 3) ? p.A3 : p.A;
  const u16* Bt = (z == 0) ? p.Bt0 : (z == 1) ? p.Bt1 : (z == 2) ? p.Bt2 : p.Bt3;
  const float* bias = (z == 0) ? p.b0 : (z == 1) ? p.b1 : (z == 2) ? p.b2 : p.b3;
  void* Cv = (z == 0) ? p.C0 : (z == 1) ? p.C1 : (z == 2) ? p.C2 : p.C3;
  int K = p.K, N = p.N;
  bool f32o = p.outFp32 && (*p.flag);

  int tid = threadIdx.x;
  int wave = tid >> 6, lane = tid & 63;
  int quad = lane >> 4, l16 = lane & 15;
  int m0 = blockIdx.y * 128, n0 = blockIdx.x * 128;
  int wm = (wave >> 1) * 64, wn = (wave & 1) * 64;

  int trow = tid >> 2;
  int tcol = (tid & 3) * 8;
  const u16* ga = A + (size_t)(m0 + trow) * K + tcol;
  const u16* gb = Bt + (size_t)(n0 + trow) * K + tcol;
  u16* lwa = As + wave * 512;
  u16* lwb = Bs + wave * 512;

  f32x4 acc[4][4] = {};

  for (int k0 = 0; k0 < K; k0 += 32) {
    __syncthreads();
    gld16(ga + k0, lwa);
    gld16(ga + (size_t)64 * K + k0, lwa + 2048);
    gld16(gb + k0, lwb);
    gld16(gb + (size_t)64 * K + k0, lwb + 2048);
    __syncthreads();
    bf16x8 af[4], bfv[4];
#pragma unroll
    for (int i = 0; i < 4; ++i) {
      af[i] = *(const bf16x8*)&As[(wm + i * 16 + l16) * 32 + quad * 8];
      bfv[i] = *(const bf16x8*)&Bs[(wn + i * 16 + l16) * 32 + quad * 8];
    }
#pragma unroll
    for (int tm = 0; tm < 4; ++tm)
#pragma unroll
      for (int tn = 0; tn < 4; ++tn)
        acc[tm][tn] = __builtin_amdgcn_mfma_f32_16x16x32_bf16(af[tm], bfv[tn], acc[tm][tn], 0, 0, 0);
  }

#pragma unroll
  for (int tm = 0; tm < 4; ++tm) {
    int row = m0 + wm + tm * 16 + quad * 4;
#pragma unroll
    for (int tn = 0; tn < 4; ++tn) {
      int col = n0 + wn + tn * 16 + l16;
      float bv = bias[col];
#pragma unroll
      for (int r = 0; r < 4; ++r) {
        float val = acc[tm][tn][r] + bv;
        if (f32o) ((float*)Cv)[(size_t)(row + r) * N + col] = val;
        else ((u16*)Cv)[(size_t)(row + r) * N + col] = f2bf(val);
      }
    }
  }
}

// ---------------- fused rel-attention v5: cached rotating pos-band slices ----------------
// Per pass p, band slice a (r-rows 64a + off_p - s0 - 65, 64 rows) is iteration-invariant:
// computed ONCE (at iter j0 = 64(a-1), or warmup for p0 a=0), stored UNMASKED in a 2-slot
// rotating buffer Bb_p[128][66]. Gather applies the rel-shift + validity:
//   e = c_l - s_l; T = s0 - j0; pass0 valid iff e <= T (== r-row in range, proved);
//   pass1 valid iff e >= T+2. Physical band row = (e + C_p + j0) & 127 (C0=64, C1=63).
// Exactly one pass active per iter except the diagonal tile j0 == s0.
__global__ __launch_bounds__(256, 3) void attn_kernel(
    const u16* __restrict__ Q, const u16* __restrict__ Kg,
    const u16* __restrict__ Vtg, const u16* __restrict__ Rg,
    const float* __restrict__ pf,
    u16* __restrict__ O) {
  __shared__ __align__(16) u16 KP[4096];      // K blocked [2][64][32] / P flat [64][64]
  __shared__ __align__(16) u16 RVs[4096];     // R slice blocked / V blocked
  __shared__ __align__(16) u16 Bb0[128 * 66]; // pass0 band, 2 rotating 64-row slots
  __shared__ __align__(16) u16 Bb1[128 * 66]; // pass1 band

  int tid = threadIdx.x, wave = tid >> 6, lane = tid & 63;
  int quad = lane >> 4, l16 = lane & 15;
  int id = blockIdx.x;
  int bh = (id & 7) + ((id >> 8) << 3);  // same-head blocks share id%8 -> same XCD
  int s0 = ((id >> 3) & 31) * 64;
  int b = bh >> 4, h = bh & 15;
  const float* pu = pf + 5 * 1024 + h * PD;
  const float* pv = pf + 6 * 1024 + h * PD;

  int arow = wave * 16 + l16;          // this lane's A-frag row
  int sl_base = wave * 16 + quad * 4;  // C-layout row base

  // staging geometry: 4 lanes cover one 64B line; wave covers 16 rows
  int srow = wave * 16 + (lane >> 2);
  int scol = (lane & 3) * 8;
  u16* kbase = KP + wave * 512;
  u16* rvbase = RVs + wave * 512;
  int kb0 = l16 * 32 + quad * 8;  // frag base into blocked [2][64][32]

  // ---- prologue: Q fragments in registers, pre-scaled by 1/8 ----
  bf16x8 qu0, qu1, qv0a, qv1a, qv0b, qv1b;
  {
    const u16* qp = Q + ((size_t)(b * SEQ + s0 + arow)) * DM + h * PD;
    int row2 = s0 + arow + 1;
    if (row2 > SEQ - 1) row2 = SEQ - 1;  // clamped row feeds only masked elements
    const u16* qp2 = Q + ((size_t)(b * SEQ + row2)) * DM + h * PD;
    u16 qa[16] __attribute__((aligned(16)));
    u16 qb[16] __attribute__((aligned(16)));
    *(uint4*)&qa[0] = *(const uint4*)(qp + quad * 8);
    *(uint4*)&qa[8] = *(const uint4*)(qp + 32 + quad * 8);
    *(uint4*)&qb[0] = *(const uint4*)(qp2 + quad * 8);
    *(uint4*)&qb[8] = *(const uint4*)(qp2 + 32 + quad * 8);
    u16 fu[16] __attribute__((aligned(16)));
    u16 fv0[16] __attribute__((aligned(16)));
    u16 fv1[16] __attribute__((aligned(16)));
#pragma unroll
    for (int j = 0; j < 8; ++j) {
      float u0 = pu[quad * 8 + j], u1 = pu[32 + quad * 8 + j];
      float v0 = pv[quad * 8 + j], v1 = pv[32 + quad * 8 + j];
      fu[j] = f2bf((bf2f(qa[j]) + u0) * 0.125f);
      fu[8 + j] = f2bf((bf2f(qa[8 + j]) + u1) * 0.125f);
      fv0[j] = f2bf((bf2f(qa[j]) + v0) * 0.125f);
      fv0[8 + j] = f2bf((bf2f(qa[8 + j]) + v1) * 0.125f);
      fv1[j] = f2bf((bf2f(qb[j]) + v0) * 0.125f);
      fv1[8 + j] = f2bf((bf2f(qb[8 + j]) + v1) * 0.125f);
    }
    __builtin_memcpy(&qu0, &fu[0], 16);
    __builtin_memcpy(&qu1, &fu[8], 16);
    __builtin_memcpy(&qv0a, &fv0[0], 16);
    __builtin_memcpy(&qv1a, &fv0[8], 16);
    __builtin_memcpy(&qv0b, &fv1[0], 16);
    __builtin_memcpy(&qv1b, &fv1[8], 16);
  }

  // R-slice DMA with address clamp (OOB rows hold garbage; gather predicate
  // provably never reads them — validity == r-row in-range)
  auto dmaR = [&](int tb0) {
    int tg = tb0 + srow;
    tg = tg < 0 ? 0 : (tg > SEQ - 1 ? SEQ - 1 : tg);
    const u16* gr = Rg + (size_t)tg * DM + h * PD + scol;
    gld16(gr, rvbase);
    gld16(gr + 32, rvbase + 2048);
  };
  // one 64-row band slice: MFMA from RVs, store unmasked into slot (base BB)
  auto slice = [&](bf16x8 fa0, bf16x8 fa1, u16* BB) {
#pragma unroll
    for (int tt = 0; tt < 4; ++tt) {
      f32x4 pacc = {};
      bf16x8 b0 = *(const bf16x8*)&RVs[kb0 + tt * 512];
      bf16x8 b1 = *(const bf16x8*)&RVs[kb0 + tt * 512 + 2048];
      pacc = __builtin_amdgcn_mfma_f32_16x16x32_bf16(fa0, b0, pacc, 0, 0, 0);
      pacc = __builtin_amdgcn_mfma_f32_16x16x32_bf16(fa1, b1, pacc, 0, 0, 0);
      int rloc = tt * 16 + l16;
      *(u32*)&BB[rloc * 66 + sl_base] = pack2(pacc[0], pacc[1]);
      *(u32*)&BB[rloc * 66 + sl_base + 2] = pack2(pacc[2], pacc[3]);
    }
  };

  float m_i[4], l_i[4];
#pragma unroll
  for (int r = 0; r < 4; ++r) { m_i[r] = -1e30f; l_i[r] = 0.f; }
  f32x4 oacc[4] = {};

  // ---- warmup: pass0 slice a=0 into Bb0 slot 0 ----
  dmaR(SEQ - 65 - s0);
  __syncthreads();  // R landed
  slice(qv0a, qv1a, Bb0);

  for (int j0 = 0; j0 < SEQ; j0 += 64) {
    int a1 = (j0 >> 6) + 1;
    int slot = (a1 & 1) << 6;
    bool p0n = (j0 <= s0);
    bool p1n = (j0 >= s0);
    __syncthreads();  // prev PV / warmup LDS reads done
    {
      const u16* gk = Kg + (size_t)(b * SEQ + j0 + srow) * DM + h * PD + scol;
      gld16(gk, kbase);
      gld16(gk + 32, kbase + 2048);
    }
    dmaR((p0n ? (SEQ - 65 - s0) : (-65 - s0)) + 64 * a1);
    __syncthreads();  // K + R landed

    // content scores -> C-layout registers
    f32x4 acc[4];
#pragma unroll
    for (int tn = 0; tn < 4; ++tn) {
      f32x4 a = {};
      bf16x8 b0 = *(const bf16x8*)&KP[kb0 + tn * 512];
      bf16x8 b1 = *(const bf16x8*)&KP[kb0 + tn * 512 + 2048];
      a = __builtin_amdgcn_mfma_f32_16x16x32_bf16(qu0, b0, a, 0, 0, 0);
      a = __builtin_amdgcn_mfma_f32_16x16x32_bf16(qu1, b1, a, 0, 0, 0);
      acc[tn] = a;
    }

    // new band slice(s): a1 for whichever pass is live
    if (p0n) slice(qv0a, qv1a, Bb0 + slot * 66);
    if (p0n && p1n) {  // diagonal tile only: restage R for pass1
      __syncthreads();
      dmaR(64 * a1 - s0 - 65);
      __syncthreads();
    }
    if (p1n) slice(qv0b, qv1b, Bb1 + slot * 66);
    __syncthreads();  // band stores visible; RVs frag reads done

    // V DMA (drains at the pre-PV barrier, overlaps gather/softmax VALU)
    {
      const u16* gv = Vtg + ((size_t)(b * NH + h) * PD + srow) * SEQ + j0 + scol;
      gld16(gv, rvbase);
      gld16(gv + 32, rvbase + 2048);
    }

    // gather-add the shifted positional scores
    int T = s0 - j0;
#pragma unroll
    for (int tn = 0; tn < 4; ++tn) {
      int cl = tn * 16 + l16;
#pragma unroll
      for (int r = 0; r < 4; ++r) {
        int e = cl - (sl_base + r);
        if (p0n) {
          int rl = (e + 64 + j0) & 127;
          float v = bf2f(Bb0[rl * 66 + sl_base + r]);
          acc[tn][r] += (e <= T) ? v : 0.f;
        }
        if (p1n) {
          int rl = (e + 63 + j0) & 127;
          float v = bf2f(Bb1[rl * 66 + sl_base + r]);
          acc[tn][r] += (e >= T + 2) ? v : 0.f;
        }
      }
    }

    // softmax in C-layout registers (scores already /8)
    float alpha_r[4];
#pragma unroll
    for (int r = 0; r < 4; ++r) {
      float v0 = acc[0][r], v1 = acc[1][r];
      float v2 = acc[2][r], v3 = acc[3][r];
      float mx = fmaxf(fmaxf(v0, v1), fmaxf(v2, v3));
      mx = rmax16(mx);
      float m_new = fmaxf(m_i[r], mx);
      float al = __expf(m_i[r] - m_new);
      u32 w0 = pack2(__expf(v0 - m_new), __expf(v1 - m_new));
      u32 w1 = pack2(__expf(v2 - m_new), __expf(v3 - m_new));
      u16 ec[4] = {(u16)w0, (u16)(w0 >> 16), (u16)w1, (u16)(w1 >> 16)};
      int row = sl_base + r;
      u16* prow_ = KP + row * 64 + l16;
#pragma unroll
      for (int cr = 0; cr < 4; ++cr) {
        int c = (cr + quad) & 3;  // quad-rotated column order: conflict-free banks
        prow_[c * 16] = ec[c];
      }
      float ssum = u2f(w0 << 16) + u2f(w0 & 0xffff0000u) + u2f(w1 << 16) + u2f(w1 & 0xffff0000u);
      ssum = rsum16(ssum);
      l_i[r] = l_i[r] * al + ssum;
      m_i[r] = m_new;
      alpha_r[r] = al;
    }
    __syncthreads();  // V landed + P visible

    // PV
    {
      bf16x8 pa0 = *(const bf16x8*)&KP[arow * 64 + quad * 8];
      bf16x8 pa1 = *(const bf16x8*)&KP[arow * 64 + 32 + quad * 8];
#pragma unroll
      for (int tp = 0; tp < 4; ++tp) {
#pragma unroll
        for (int r = 0; r < 4; ++r) oacc[tp][r] *= alpha_r[r];
        bf16x8 b0 = *(const bf16x8*)&RVs[kb0 + tp * 512];
        bf16x8 b1 = *(const bf16x8*)&RVs[kb0 + tp * 512 + 2048];
        oacc[tp] = __builtin_amdgcn_mfma_f32_16x16x32_bf16(pa0, b0, oacc[tp], 0, 0, 0);
        oacc[tp] = __builtin_amdgcn_mfma_f32_16x16x32_bf16(pa1, b1, oacc[tp], 0, 0, 0);
      }
    }
  }

  // epilogue
#pragma unroll
  for (int r = 0; r < 4; ++r) l_i[r] = 1.f / l_i[r];
#pragma unroll
  for (int tp = 0; tp < 4; ++tp) {
    int pcol = tp * 16 + l16;
#pragma unroll
    for (int r = 0; r < 4; ++r) {
      int sg = s0 + sl_base + r;
      O[((size_t)(b * SEQ + sg)) * DM + h * PD + pcol] = f2bf(oacc[tp][r] * l_i[r]);
    }
  }
}

extern "C" void kernel_launch(void* const* d_in, const int* in_sizes, int n_in,
                              void* d_out, int out_size, void* d_ws, size_t ws_size,
                              hipStream_t stream) {
  (void)in_sizes; (void)n_in; (void)out_size; (void)ws_size;
  const void* x  = d_in[0];
  const void* Wq = d_in[1];
  const void* bq = d_in[2];
  const void* Wk = d_in[3];
  const void* bk = d_in[4];
  const void* Wv = d_in[5];
  const void* bv = d_in[6];
  const void* Wp = d_in[7];
  const void* bp = d_in[8];
  const void* Wo = d_in[9];
  const void* bo = d_in[10];
  const void* u  = d_in[11];
  const void* v  = d_in[12];

  char* base = (char*)d_ws;
  int* flag = (int*)base;
  float* pf = (float*)(base + 64);                       // 7168 floats
  u16* wbase = (u16*)(base + 64 + 7168 * 4);
  u16* WT   = wbase;                                     // 5M elems
  u16* xb   = WT + (size_t)5 * DM * DM;                  // 4M (aliased: Vtb)
  u16* sinb = xb + (size_t)2 * SEQ * DM;                 // 2M
  u16* Qb   = sinb + (size_t)SEQ * DM;                   // 4M
  u16* Kb   = Qb + (size_t)2 * SEQ * DM;                 // 4M
  u16* Vb   = Kb + (size_t)2 * SEQ * DM;                 // 4M (aliased: attn out)
  u16* Rb   = Vb + (size_t)2 * SEQ * DM;                 // 2M
  u16* Vtb  = xb;   // x consumed by QKV gemm before transpose_v writes here
  u16* Ab   = Vb;   // V consumed by transpose_v before attention writes here

  detect_kernel<<<1, 256, 0, stream>>>((const u16*)Wq, flag);

  convert_x_kernel<<<(2 * SEQ * DM) / 1024, 256, 0, stream>>>(x, xb, flag);
  ParamPtrs pp;
  pp.p[0] = bq; pp.p[1] = bk; pp.p[2] = bv; pp.p[3] = bp; pp.p[4] = bo;
  pp.p[5] = u;  pp.p[6] = v;
  convert_params_kernel<<<28, 256, 0, stream>>>(pp, pf, flag);

  sinusoid_kernel<<<(SEQ * DM) / 256, 256, 0, stream>>>(sinb);
  transpose5_kernel<<<dim3(16, 16, 5), 256, 0, stream>>>(Wq, Wk, Wv, Wp, Wo, WT, flag);

  // fused QKV + positional-projection GEMM (z = 0..2: x @ {Wq,Wk,Wv}; z = 3: sin @ Wp)
  GemmArgs qkv;
  qkv.A = xb; qkv.A3 = sinb;
  qkv.Bt0 = WT; qkv.Bt1 = WT + (size_t)DM * DM; qkv.Bt2 = WT + (size_t)2 * DM * DM;
  qkv.Bt3 = WT + (size_t)3 * DM * DM;
  qkv.b0 = pf; qkv.b1 = pf + 1024; qkv.b2 = pf + 2048; qkv.b3 = pf + 3072;
  qkv.C0 = Qb; qkv.C1 = Kb; qkv.C2 = Vb; qkv.C3 = Rb;
  qkv.N = DM; qkv.K = DM; qkv.M3 = SEQ; qkv.flag = flag; qkv.outFp32 = 0;
  gemm_bt_kernel<<<dim3(8, 32, 4), 256, 0, stream>>>(qkv);

  transpose_v_kernel<<<dim3(32, 32), 256, 0, stream>>>(Vb, Vtb);
  attn_kernel<<<dim3(1024), 256, 0, stream>>>(Qb, Kb, Vtb, Rb, pf, Ab);

  GemmArgs fo;
  fo.A = Ab; fo.A3 = Ab;
  fo.Bt0 = WT + (size_t)4 * DM * DM; fo.Bt1 = fo.Bt0; fo.Bt2 = fo.Bt0; fo.Bt3 = fo.Bt0;
  fo.b0 = pf + 4096; fo.b1 = fo.b0; fo.b2 = fo.b0; fo.b3 = fo.b0;
  fo.C0 = d_out; fo.C1 = d_out; fo.C2 = d_out; fo.C3 = d_out;
  fo.N = DM; fo.K = DM; fo.M3 = 0; fo.flag = flag; fo.outFp32 = 1;
  gemm_bt_kernel<<<dim3(8, 32, 1), 256, 0, stream>>>(fo);
}